// Round 9
// baseline (295.114 us; speedup 1.0000x reference)
//
#include <hip/hip_runtime.h>

typedef unsigned short u16;
typedef unsigned int u32;
typedef u16 u16x4 __attribute__((ext_vector_type(4)));
typedef u16 u16x8 __attribute__((ext_vector_type(8)));
typedef u32 u32x4 __attribute__((ext_vector_type(4)));
typedef __bf16 bf16x8 __attribute__((ext_vector_type(8)));
typedef float f32x4 __attribute__((ext_vector_type(4)));

#define NB   2
#define NQH  32
#define NKH  8
#define SEQ  2048
#define DIM  128
#define QT   128                      // q rows per block (32 per wave, 2 frag sets)
#define NT   32                       // 64-key tiles per head
#define HALFU16 4096                  // 32*128 u16 = 8KB (V half image)
#define TILEU16 8192                  // 64*128 u16 = 16KB per tile image
#define HEADU16 (NT * TILEU16)
#define VOFFU16 (16 * HEADU16)        // V images after 16 heads of K

__device__ __forceinline__ u16 f2bf(float f) {
  u32 u = __builtin_bit_cast(u32, f);
  u += 0x7FFFu + ((u >> 16) & 1u);
  return (u16)(u >> 16);
}
__device__ __forceinline__ u32 cvtpk(float lo, float hi) {
  u32 r;
  asm("v_cvt_pk_bf16_f32 %0, %1, %2" : "=v"(r) : "v"(lo), "v"(hi));
  return r;
}
__device__ __forceinline__ f32x4 mfma16(u16x8 a, u16x8 b, f32x4 c) {
  return __builtin_amdgcn_mfma_f32_16x16x32_bf16(
      __builtin_bit_cast(bf16x8, a), __builtin_bit_cast(bf16x8, b), c, 0, 0, 0);
}
__device__ __forceinline__ void gl_lds16(const u16* g, u16* l) {
  __builtin_amdgcn_global_load_lds(
      (const __attribute__((address_space(1))) u32*)(const void*)g,
      (__attribute__((address_space(3))) u32*)(void*)l, 16, 0, 0);
}

// ---- pre-pass (unchanged layout from R8, verified) ----
// K tile image: u16 idx j*128 + (dm ^ ((j&7)<<3)) = K[j][dm], j=0..63.
// V tile image: two 32-key halves; half image [128 d][32 slots]:
//   u16 idx half*4096 + d*32 + 8*grp + i, grp = gr^((d>>1)&3),
//   slot s=8*gr+i holds key 32*half + 16*(i>>2) + 4*gr + (i&3).
__global__ __launch_bounds__(256) void prep(const float* __restrict__ Kg,
                                            const float* __restrict__ Vg,
                                            u16* __restrict__ ws) {
  const int bid = blockIdx.x;          // 0..1023 : first 512 K, next 512 V
  const int tid = threadIdx.x;
  const int tile = bid & 511;          // head*32 + kt
  const size_t sbase = (size_t)(tile >> 5) * SEQ * DIM + (size_t)(tile & 31) * 64 * DIM;
  if (bid < 512) {
    const float* src = Kg + sbase;
    u16* img = ws + (size_t)tile * TILEU16;
    #pragma unroll
    for (int u = 0; u < 8; ++u) {
      int c = tid + 256 * u;           // float4 chunk 0..2047
      int j = c >> 5;
      int dm = (c & 31) * 4;
      float4 v = *(const float4*)(src + j * DIM + dm);
      u16x4 w = { f2bf(v.x), f2bf(v.y), f2bf(v.z), f2bf(v.w) };
      *(u16x4*)(img + j * 128 + (dm ^ ((j & 7) << 3))) = w;
    }
  } else {
    const float* src = Vg + sbase;
    u16* img = ws + VOFFU16 + (size_t)tile * TILEU16;
    #pragma unroll
    for (int u = 0; u < 4; ++u) {
      int g = tid + 256 * u;           // u16x8 granule 0..1023
      int half = g >> 9;
      int gg = g & 511;
      int d = gg >> 2;
      int grp = gg & 3;                // stored granule slot
      int gr = grp ^ ((d >> 1) & 3);   // logical lg group
      u16x8 w;
      #pragma unroll
      for (int i = 0; i < 8; ++i) {
        int key = 16 * (i >> 2) + 4 * gr + (i & 3);
        w[i] = f2bf(src[(32 * half + key) * DIM + d]);
      }
      *(u16x8*)(img + half * HALFU16 + d * 32 + grp * 8) = w;
    }
  }
}

__global__ __launch_bounds__(256) void gqa_fwd(const float* __restrict__ Qg,
                                               const u16* __restrict__ ws,
                                               float* __restrict__ Og) {
  __shared__ __align__(16) u16 sK[2][TILEU16];
  __shared__ __align__(16) u16 sV[2][TILEU16];

  const int tid  = threadIdx.x;
  const int lane = tid & 63;
  const int wave = tid >> 6;
  const int lr   = lane & 15;   // q-row within 16
  const int lg   = lane >> 4;   // group 0..3

  // XCD-aware swizzle: 1024 blocks, 8 XCDs -> contiguous runs of 128.
  const int id = blockIdx.x;           // 0..1023
  const int wg = (id & 7) * 128 + (id >> 3);
  const int qtile = wg & 15;           // 0..15
  const int bqh   = wg >> 4;           // 0..63
  const int b     = bqh >> 5;
  const int qh    = bqh & 31;
  const int kh    = qh >> 2;           // G = 4

  const size_t qbase = (size_t)bqh * SEQ * DIM;
  const u16* imgK = ws + (size_t)(b * NKH + kh) * HEADU16;
  const u16* imgV = imgK + VOFFU16;
  const int qrow_w = qtile * QT + wave * 32;

  // log2-domain scale: 1/sqrt(128) * log2(e)
  const float s2 = 0.08838834764831845f * 1.4426950408889634f;

  // Two Q frag sets: qf0 rows qrow_w+lr, qf1 rows qrow_w+16+lr
  u16x8 qf0[4], qf1[4];
  #pragma unroll
  for (int s = 0; s < 4; ++s) {
    const float* qp0 = Qg + qbase + (size_t)(qrow_w + lr) * DIM + 32 * s + 8 * lg;
    float4 a = *(const float4*)qp0;
    float4 c = *(const float4*)(qp0 + 4);
    qf0[s] = __builtin_bit_cast(u16x8, u32x4{
        cvtpk(a.x * s2, a.y * s2), cvtpk(a.z * s2, a.w * s2),
        cvtpk(c.x * s2, c.y * s2), cvtpk(c.z * s2, c.w * s2) });
    const float* qp1 = qp0 + 16 * DIM;
    float4 e = *(const float4*)qp1;
    float4 f = *(const float4*)(qp1 + 4);
    qf1[s] = __builtin_bit_cast(u16x8, u32x4{
        cvtpk(e.x * s2, e.y * s2), cvtpk(e.z * s2, e.w * s2),
        cvtpk(f.x * s2, f.y * s2), cvtpk(f.z * s2, f.w * s2) });
  }

  const f32x4 zero4 = {0.f, 0.f, 0.f, 0.f};
  f32x4 o0[8], o1[8];
  #pragma unroll
  for (int dt = 0; dt < 8; ++dt) { o0[dt] = zero4; o1[dt] = zero4; }
  float m0 = -3.0e38f, m1 = -3.0e38f, l0 = 0.f, l1 = 0.f;

  const int swzK = (lr & 7) << 3;
  const int swzV = (lg ^ ((lr >> 1) & 3)) << 3;

  auto issue = [&](int t, int pb) {
    const u16* gK = imgK + (size_t)t * TILEU16;
    const u16* gV = imgV + (size_t)t * TILEU16;
    #pragma unroll
    for (int u = 0; u < 4; ++u) {
      const int q = u * 4 + wave;      // 1KB chunk 0..15
      gl_lds16(gK + q * 512 + lane * 8, &sK[pb][q * 512]);
      gl_lds16(gV + q * 512 + lane * 8, &sV[pb][q * 512]);
    }
  };

  auto body = [&](int T, int PB) {
    issue((T + 1) & (NT - 1), PB ^ 1);      // prefetch next tile
    asm volatile("s_waitcnt vmcnt(8)" ::: "memory");  // this tile's 8 loads done
    __builtin_amdgcn_s_barrier();           // keep prefetch in flight

    // ---- S^T = K Q^T for both row-sets; each kf read serves both
    f32x4 s0[4] = {zero4, zero4, zero4, zero4};
    f32x4 s1[4] = {zero4, zero4, zero4, zero4};
    __builtin_amdgcn_s_setprio(1);
    #pragma unroll
    for (int jt = 0; jt < 4; ++jt) {
      #pragma unroll
      for (int s = 0; s < 4; ++s) {
        u16x8 kf = *(const u16x8*)&sK[PB][(jt * 16 + lr) * 128 + ((32 * s + 8 * lg) ^ swzK)];
        s0[jt] = mfma16(kf, qf0[s], s0[jt]);
        s1[jt] = mfma16(kf, qf1[s], s1[jt]);
      }
    }
    __builtin_amdgcn_s_setprio(0);

    // ---- online softmax (log2 domain), per set; q-row = lr per lane
    float t0 = s0[0][0], t1 = s1[0][0];
    #pragma unroll
    for (int jt = 0; jt < 4; ++jt)
      #pragma unroll
      for (int e = 0; e < 4; ++e) {
        t0 = fmaxf(t0, s0[jt][e]);
        t1 = fmaxf(t1, s1[jt][e]);
      }
    t0 = fmaxf(t0, __shfl_xor(t0, 16, 64)); t0 = fmaxf(t0, __shfl_xor(t0, 32, 64));
    t1 = fmaxf(t1, __shfl_xor(t1, 16, 64)); t1 = fmaxf(t1, __shfl_xor(t1, 32, 64));

    if (!__all((t0 - m0 <= 11.0f) && (t1 - m1 <= 11.0f))) {  // defer-max
      float mn0 = fmaxf(m0, t0), c0 = exp2f(m0 - mn0);
      float mn1 = fmaxf(m1, t1), c1 = exp2f(m1 - mn1);
      m0 = mn0; m1 = mn1; l0 *= c0; l1 *= c1;
      #pragma unroll
      for (int e = 0; e < 4; ++e) {
        float co0 = __shfl(c0, 4 * lg + e, 64);
        float co1 = __shfl(c1, 4 * lg + e, 64);
        #pragma unroll
        for (int dt = 0; dt < 8; ++dt) { o0[dt][e] *= co0; o1[dt][e] *= co1; }
      }
    }

    float r0 = 0.f, r1 = 0.f;
    u32 pk0[8], pk1[8];
    #pragma unroll
    for (int jt = 0; jt < 4; ++jt) {
      float a0 = exp2f(s0[jt][0] - m0), b0 = exp2f(s0[jt][1] - m0);
      float c0 = exp2f(s0[jt][2] - m0), d0 = exp2f(s0[jt][3] - m0);
      r0 += (a0 + b0) + (c0 + d0);
      pk0[2 * jt] = cvtpk(a0, b0); pk0[2 * jt + 1] = cvtpk(c0, d0);
      float a1 = exp2f(s1[jt][0] - m1), b1 = exp2f(s1[jt][1] - m1);
      float c1 = exp2f(s1[jt][2] - m1), d1 = exp2f(s1[jt][3] - m1);
      r1 += (a1 + b1) + (c1 + d1);
      pk1[2 * jt] = cvtpk(a1, b1); pk1[2 * jt + 1] = cvtpk(c1, d1);
    }
    r0 += __shfl_xor(r0, 16, 64); r0 += __shfl_xor(r0, 32, 64); l0 += r0;
    r1 += __shfl_xor(r1, 16, 64); r1 += __shfl_xor(r1, 32, 64); l1 += r1;

    // ---- A-frags: pure bitcast (sigma folded into V image); ks = key 32-half
    u16x8 a00 = __builtin_bit_cast(u16x8, u32x4{pk0[0], pk0[1], pk0[2], pk0[3]});
    u16x8 a01 = __builtin_bit_cast(u16x8, u32x4{pk0[4], pk0[5], pk0[6], pk0[7]});
    u16x8 a10 = __builtin_bit_cast(u16x8, u32x4{pk1[0], pk1[1], pk1[2], pk1[3]});
    u16x8 a11 = __builtin_bit_cast(u16x8, u32x4{pk1[4], pk1[5], pk1[6], pk1[7]});

    // ---- O += P V : each vf read serves both row-sets
    __builtin_amdgcn_s_setprio(1);
    #pragma unroll
    for (int dt = 0; dt < 8; ++dt) {
      u16x8 vf0 = *(const u16x8*)&sV[PB][(16 * dt + lr) * 32 + swzV];
      u16x8 vf1 = *(const u16x8*)&sV[PB][HALFU16 + (16 * dt + lr) * 32 + swzV];
      o0[dt] = mfma16(a00, vf0, o0[dt]);
      o1[dt] = mfma16(a10, vf0, o1[dt]);
      o0[dt] = mfma16(a01, vf1, o0[dt]);
      o1[dt] = mfma16(a11, vf1, o1[dt]);
    }
    __builtin_amdgcn_s_setprio(0);
    __builtin_amdgcn_s_barrier();           // all waves done reading buf[PB]
  };

  issue(0, 0);
  for (int T = 0; T < NT; ++T) body(T, T & 1);
  asm volatile("s_waitcnt vmcnt(0)" ::: "memory");  // drain wrap-around prefetch

  // ---- epilogue: rows q = 4lg+e (set0) and 16+4lg+e (set1)
  float li0 = 1.0f / l0, li1 = 1.0f / l1;
  #pragma unroll
  for (int e = 0; e < 4; ++e) {
    float lo0 = __shfl(li0, 4 * lg + e, 64);
    float lo1 = __shfl(li1, 4 * lg + e, 64);
    float* op0 = Og + qbase + (size_t)(qrow_w + 4 * lg + e) * DIM;
    float* op1 = op0 + 16 * DIM;
    #pragma unroll
    for (int dt = 0; dt < 8; ++dt) {
      op0[dt * 16 + lr] = o0[dt][e] * lo0;
      op1[dt * 16 + lr] = o1[dt][e] * lo1;
    }
  }
}

extern "C" void kernel_launch(void* const* d_in, const int* in_sizes, int n_in,
                              void* d_out, int out_size, void* d_ws, size_t ws_size,
                              hipStream_t stream) {
  const float* Q = (const float*)d_in[0];
  const float* K = (const float*)d_in[1];
  const float* V = (const float*)d_in[2];
  float* O = (float*)d_out;
  u16* ws = (u16*)d_ws;
  prep<<<dim3(1024), 256, 0, stream>>>(K, V, ws);
  gqa_fwd<<<dim3((SEQ / QT) * NB * NQH), 256, 0, stream>>>(Q, ws, O);
}

// Round 10
// 288.436 us; speedup vs baseline: 1.0232x; 1.0232x over previous
//
#include <hip/hip_runtime.h>

typedef unsigned short u16;
typedef unsigned int u32;
typedef u16 u16x4 __attribute__((ext_vector_type(4)));
typedef u16 u16x8 __attribute__((ext_vector_type(8)));
typedef u32 u32x4 __attribute__((ext_vector_type(4)));
typedef __bf16 bf16x8 __attribute__((ext_vector_type(8)));
typedef float f32x16 __attribute__((ext_vector_type(16)));

#define NB   2
#define NQH  32
#define NKH  8
#define SEQ  2048
#define DIM  128
#define QT   128                      // q rows per block (32 per wave, 32x32 MFMA)
#define NT   32                       // 64-key tiles per head
#define TILEU16 8192                  // 64*128 u16 = 16KB per tile image
#define HEADU16 (NT * TILEU16)
#define VOFFU16 (16 * HEADU16)

__device__ __forceinline__ u16 f2bf(float f) {
  u32 u = __builtin_bit_cast(u32, f);
  u += 0x7FFFu + ((u >> 16) & 1u);
  return (u16)(u >> 16);
}
__device__ __forceinline__ u32 cvtpk(float lo, float hi) {
  u32 r;
  asm("v_cvt_pk_bf16_f32 %0, %1, %2" : "=v"(r) : "v"(lo), "v"(hi));
  return r;
}
__device__ __forceinline__ f32x16 mfma32(u16x8 a, u16x8 b, f32x16 c) {
  return __builtin_amdgcn_mfma_f32_32x32x16_bf16(
      __builtin_bit_cast(bf16x8, a), __builtin_bit_cast(bf16x8, b), c, 0, 0, 0);
}
__device__ __forceinline__ void gl_lds16(const u16* g, u16* l) {
  __builtin_amdgcn_global_load_lds(
      (const __attribute__((address_space(1))) u32*)(const void*)g,
      (__attribute__((address_space(3))) u32*)(void*)l, 16, 0, 0);
}

// ---- pre-pass (R6 layout, verified) ----
// K tile image: u16 idx j*128 + (dm ^ ((j&7)<<3)) = K[j][dm]
// V tile image: u16 idx d*64 + ((8pg) ^ ((d&7)<<3)) + i = V[key(8pg+i)][d],
//   key(p) = swap bits 2<->3 of p.
__global__ __launch_bounds__(256) void prep(const float* __restrict__ Kg,
                                            const float* __restrict__ Vg,
                                            u16* __restrict__ ws) {
  const int bid = blockIdx.x;          // 0..1023 : first 512 K, next 512 V
  const int tid = threadIdx.x;
  const int tile = bid & 511;          // head*32 + kt
  const size_t sbase = (size_t)(tile >> 5) * SEQ * DIM + (size_t)(tile & 31) * 64 * DIM;
  if (bid < 512) {
    const float* src = Kg + sbase;
    u16* img = ws + (size_t)tile * TILEU16;
    #pragma unroll
    for (int u = 0; u < 8; ++u) {
      int c = tid + 256 * u;           // float4 chunk 0..2047
      int j = c >> 5;
      int dm = (c & 31) * 4;
      float4 v = *(const float4*)(src + j * DIM + dm);
      u16x4 w = { f2bf(v.x), f2bf(v.y), f2bf(v.z), f2bf(v.w) };
      *(u16x4*)(img + j * 128 + (dm ^ ((j & 7) << 3))) = w;
    }
  } else {
    const float* src = Vg + sbase;
    u16* img = ws + VOFFU16 + (size_t)tile * TILEU16;
    #pragma unroll
    for (int u = 0; u < 4; ++u) {
      int c = tid + 256 * u;           // u16x8 granule 0..1023
      int d = c >> 3;
      int pg = c & 7;
      u16x8 w;
      #pragma unroll
      for (int i = 0; i < 8; ++i) {
        int p = 8 * pg + i;
        int key = (p & ~12) | ((p & 8) >> 1) | ((p & 4) << 1);  // swap bits 2,3
        w[i] = f2bf(src[key * DIM + d]);
      }
      *(u16x8*)(img + d * 64 + ((8 * pg) ^ ((d & 7) << 3))) = w;
    }
  }
}

__global__ __launch_bounds__(256) void gqa_fwd(const float* __restrict__ Qg,
                                               const u16* __restrict__ ws,
                                               float* __restrict__ Og) {
  __shared__ __align__(16) u16 sK[2][TILEU16];
  __shared__ __align__(16) u16 sV[2][TILEU16];

  const int tid  = threadIdx.x;
  const int lane = tid & 63;
  const int wave = tid >> 6;
  const int l31  = lane & 31;
  const int h    = lane >> 5;

  // XCD-aware swizzle: 1024 blocks, 8 XCDs -> contiguous runs of 128.
  const int id = blockIdx.x;
  const int wg = (id & 7) * 128 + (id >> 3);
  const int qtile = wg & 15;
  const int bqh   = wg >> 4;
  const int b     = bqh >> 5;
  const int qh    = bqh & 31;
  const int kh    = qh >> 2;           // G = 4

  const size_t qbase = (size_t)bqh * SEQ * DIM;
  const u16* imgK = ws + (size_t)(b * NKH + kh) * HEADU16;
  const u16* imgV = imgK + VOFFU16;
  const int qrow_w = qtile * QT + wave * 32;

  const float s2 = 0.08838834764831845f * 1.4426950408889634f;  // /sqrt(128)*log2e

  // Q frags (B-operand 32x32x16): qf[s8][e] = Q[q=l31][d=16*s8+8*h+e] * s2
  u16x8 qf[8];
  #pragma unroll
  for (int s8 = 0; s8 < 8; ++s8) {
    const float* qp = Qg + qbase + (size_t)(qrow_w + l31) * DIM + 16 * s8 + 8 * h;
    float4 a = *(const float4*)qp;
    float4 c = *(const float4*)(qp + 4);
    qf[s8] = __builtin_bit_cast(u16x8, u32x4{
        cvtpk(a.x * s2, a.y * s2), cvtpk(a.z * s2, a.w * s2),
        cvtpk(c.x * s2, c.y * s2), cvtpk(c.z * s2, c.w * s2) });
  }

  f32x16 oacc[4];
  #pragma unroll
  for (int dt = 0; dt < 4; ++dt)
    #pragma unroll
    for (int r = 0; r < 16; ++r) oacc[dt][r] = 0.f;
  float mrow = -3.0e38f, lrow = 0.f;

  const int swz = (l31 & 7) << 3;

  auto issueK = [&](int t, int pb) {
    const u16* g = imgK + (size_t)t * TILEU16;
    #pragma unroll
    for (int u = 0; u < 4; ++u) {
      const int q = u * 4 + wave;
      gl_lds16(g + q * 512 + lane * 8, &sK[pb][q * 512]);
    }
  };
  auto issueV = [&](int t, int pb) {
    const u16* g = imgV + (size_t)t * TILEU16;
    #pragma unroll
    for (int u = 0; u < 4; ++u) {
      const int q = u * 4 + wave;
      gl_lds16(g + q * 512 + lane * 8, &sV[pb][q * 512]);
    }
  };

  f32x16 sA, sB;
  auto qk = [&](int nb) {   // 16 MFMA: sA = keys 0-31, sB = keys 32-63
    #pragma unroll
    for (int r = 0; r < 16; ++r) { sA[r] = 0.f; sB[r] = 0.f; }
    __builtin_amdgcn_s_setprio(1);
    #pragma unroll
    for (int s8 = 0; s8 < 8; ++s8) {
      u16x8 kf0 = *(const u16x8*)&sK[nb][l31 * 128 + ((16 * s8 + 8 * h) ^ swz)];
      u16x8 kf1 = *(const u16x8*)&sK[nb][(32 + l31) * 128 + ((16 * s8 + 8 * h) ^ swz)];
      sA = mfma32(kf0, qf[s8], sA);
      sB = mfma32(kf1, qf[s8], sB);
    }
    __builtin_amdgcn_s_setprio(0);
  };
  auto pv_c = [&](int pb, int c, u16x8 a) {   // 4 MFMA with af chunk c
    __builtin_amdgcn_s_setprio(1);
    #pragma unroll
    for (int dt = 0; dt < 4; ++dt) {
      u16x8 vf = *(const u16x8*)&sV[pb][(32 * dt + l31) * 64 + ((16 * c + 8 * h) ^ swz)];
      oacc[dt] = mfma32(a, vf, oacc[dt]);
    }
    __builtin_amdgcn_s_setprio(0);
  };
  // exp chunk: 8 exps of src[base..base+7] -> af word, accumulate rsum
  auto expchunk = [&](f32x16& s, int base, float m, float& rsum) -> u16x8 {
    float e0 = exp2f(s[base+0] - m), e1 = exp2f(s[base+1] - m);
    float e2 = exp2f(s[base+2] - m), e3 = exp2f(s[base+3] - m);
    float e4 = exp2f(s[base+4] - m), e5 = exp2f(s[base+5] - m);
    float e6 = exp2f(s[base+6] - m), e7 = exp2f(s[base+7] - m);
    rsum += ((e0 + e1) + (e2 + e3)) + ((e4 + e5) + (e6 + e7));
    return __builtin_bit_cast(u16x8, u32x4{cvtpk(e0, e1), cvtpk(e2, e3),
                                           cvtpk(e4, e5), cvtpk(e6, e7)});
  };
  auto rescale_o = [&](float corr) {
    #pragma unroll
    for (int r = 0; r < 16; ++r) {
      float co = __shfl(corr, (r & 3) + 8 * (r >> 2) + 4 * h, 64);
      oacc[0][r] *= co; oacc[1][r] *= co; oacc[2][r] *= co; oacc[3][r] *= co;
    }
  };

  u16x8 afA[4], afB[4];

  // ---- prologue: stage K0,V0,K1; QK(0); full softmax -> afA ----
  issueK(0, 0); issueV(0, 0); issueK(1, 1);
  asm volatile("s_waitcnt vmcnt(8)" ::: "memory");   // K0 done
  __builtin_amdgcn_s_barrier();
  qk(0);
  {
    float tmax = sA[0];
    #pragma unroll
    for (int r = 0; r < 16; ++r) tmax = fmaxf(tmax, fmaxf(sA[r], sB[r]));
    tmax = fmaxf(tmax, __shfl_xor(tmax, 32, 64));
    mrow = tmax;
    float rs = 0.f;
    afA[0] = expchunk(sA, 0, mrow, rs);
    afA[1] = expchunk(sA, 8, mrow, rs);
    afA[2] = expchunk(sB, 0, mrow, rs);
    afA[3] = expchunk(sB, 8, mrow, rs);
    rs += __shfl_xor(rs, 32, 64);
    lrow = rs;
  }
  __builtin_amdgcn_s_barrier();   // all waves done reading sK[0] before body0 overwrite

  // ---- body(i): PV(i) with afO, QK(i+1)+softmax(i+1) -> afN ----
  auto body = [&](int i, u16x8 (&afO)[4], u16x8 (&afN)[4]) {
    const int pb = i & 1;
    issueK((i + 2) & (NT - 1), pb);          // K two ahead  (sK[pb]: K(i) consumed)
    issueV((i + 1) & (NT - 1), pb ^ 1);      // V one ahead  (sV[pb^1]: V(i-1) consumed)
    asm volatile("s_waitcnt vmcnt(8)" ::: "memory");  // K(i+1), V(i) complete
    __builtin_amdgcn_s_barrier();

    qk(pb ^ 1);                              // QK(i+1) from sK[(i+1)&1]
    pv_c(pb, 0, afO[0]);                     // PV(i) chunk 0 (independent of softmax)

    float tmax = sA[0];
    #pragma unroll
    for (int r = 0; r < 16; ++r) tmax = fmaxf(tmax, fmaxf(sA[r], sB[r]));
    tmax = fmaxf(tmax, __shfl_xor(tmax, 32, 64));

    if (__all(tmax - mrow <= 11.0f)) {       // defer-max fast path: interleave
      float rs = 0.f;
      afN[0] = expchunk(sA, 0, mrow, rs);
      pv_c(pb, 1, afO[1]);
      afN[1] = expchunk(sA, 8, mrow, rs);
      pv_c(pb, 2, afO[2]);
      afN[2] = expchunk(sB, 0, mrow, rs);
      pv_c(pb, 3, afO[3]);
      afN[3] = expchunk(sB, 8, mrow, rs);
      rs += __shfl_xor(rs, 32, 64);
      lrow += rs;
    } else {                                 // rare: finish PV, rescale, then exps
      pv_c(pb, 1, afO[1]);
      pv_c(pb, 2, afO[2]);
      pv_c(pb, 3, afO[3]);
      float mn = fmaxf(mrow, tmax);
      float corr = exp2f(mrow - mn);
      mrow = mn;
      rescale_o(corr);
      float rs = 0.f;
      afN[0] = expchunk(sA, 0, mrow, rs);
      afN[1] = expchunk(sA, 8, mrow, rs);
      afN[2] = expchunk(sB, 0, mrow, rs);
      afN[3] = expchunk(sB, 8, mrow, rs);
      rs += __shfl_xor(rs, 32, 64);
      lrow = lrow * corr + rs;
    }
    __builtin_amdgcn_s_barrier();            // protect buffers before next overwrite
  };

  for (int i2 = 0; i2 < 15; ++i2) {
    body(2 * i2, afA, afB);
    body(2 * i2 + 1, afB, afA);
  }
  body(30, afA, afB);                        // produces af(31) in afB

  // ---- tail: PV(31) ----
  asm volatile("s_waitcnt vmcnt(0)" ::: "memory");   // V(31) (and stray wraps) done
  __builtin_amdgcn_s_barrier();
  pv_c(31 & 1, 0, afB[0]);
  pv_c(31 & 1, 1, afB[1]);
  pv_c(31 & 1, 2, afB[2]);
  pv_c(31 & 1, 3, afB[3]);

  // ---- epilogue: O[q = qrow_w+(r&3)+8*(r>>2)+4h][d = 32*dt + l31] / lrow
  float linv = 1.0f / lrow;
  #pragma unroll
  for (int r = 0; r < 16; ++r) {
    const int ql = (r & 3) + 8 * (r >> 2) + 4 * h;
    float li = __shfl(linv, ql, 64);
    float* op = Og + qbase + (size_t)(qrow_w + ql) * DIM + l31;
    op[0]  = oacc[0][r] * li;
    op[32] = oacc[1][r] * li;
    op[64] = oacc[2][r] * li;
    op[96] = oacc[3][r] * li;
  }
}

extern "C" void kernel_launch(void* const* d_in, const int* in_sizes, int n_in,
                              void* d_out, int out_size, void* d_ws, size_t ws_size,
                              hipStream_t stream) {
  const float* Q = (const float*)d_in[0];
  const float* K = (const float*)d_in[1];
  const float* V = (const float*)d_in[2];
  float* O = (float*)d_out;
  u16* ws = (u16*)d_ws;
  prep<<<dim3(1024), 256, 0, stream>>>(K, V, ws);
  gqa_fwd<<<dim3((SEQ / QT) * NB * NQH), 256, 0, stream>>>(Q, ws, O);
}